// Round 4
// baseline (577.789 us; speedup 1.0000x reference)
//
#include <hip/hip_runtime.h>

#define M_DIM 16384
#define N_DIM 1024
#define K_DIM 4096

#define BM 256
#define BN 256
#define BK 64
#define NT (K_DIM / BK)

typedef __attribute__((ext_vector_type(4))) float f32x4;
typedef __attribute__((ext_vector_type(8))) short bf16x8;
typedef __attribute__((ext_vector_type(8))) unsigned short u16x8;

static __device__ __forceinline__ short f2bf(float f) {
  union { __bf16 h; short s; } u;
  u.h = (__bf16)f;   // RNE; pairs pack into v_cvt_pk_bf16_f32
  return u.s;
}

static __device__ __forceinline__ void load_lds16(const void* g, void* l) {
  __builtin_amdgcn_global_load_lds(
      (const __attribute__((address_space(1))) void*)g,
      (__attribute__((address_space(3))) void*)l, 16, 0, 0);
}

// ---------- prepass: WbT[n][k] = bf16(sign(W[k][n])) ----------
__global__ __launch_bounds__(256) void wsign_transpose(
    const float* __restrict__ W, unsigned short* __restrict__ WbT) {
  __shared__ unsigned short tile[64][72];
  const int t  = (int)threadIdx.x;
  const int k0 = (int)(blockIdx.x >> 4) * 64;
  const int n0 = (int)(blockIdx.x & 15) * 64;
#pragma unroll
  for (int p = 0; p < 4; ++p) {
    const int r = p * 16 + (t >> 4);
    const int c = (t & 15) * 4;
    const float* src = W + (size_t)(k0 + r) * N_DIM + n0 + c;
#pragma unroll
    for (int j = 0; j < 4; ++j) {
      const float w = src[j];
      tile[r][c + j] = (w > 0.f) ? (unsigned short)0x3F80u
                                 : ((w < 0.f) ? (unsigned short)0xBF80u
                                              : (unsigned short)0u);
    }
  }
  __syncthreads();
  const int n  = t >> 2;
  const int kg = (t & 3) * 16;
  u16x8 o0, o1;
#pragma unroll
  for (int j = 0; j < 8; ++j) o0[j] = tile[kg + j][n];
#pragma unroll
  for (int j = 0; j < 8; ++j) o1[j] = tile[kg + 8 + j][n];
  unsigned short* dst = WbT + (size_t)(n0 + n) * K_DIM + k0 + kg;
  *(u16x8*)dst       = o0;
  *(u16x8*)(dst + 8) = o1;
}

// ---------- main GEMM: 256x256, BK=64, 8 waves ----------
// 4 phases/K-tile; every MFMA consumes ds_reads issued >=1 phase earlier
// (counted lgkmcnt), loads stay in flight across barriers (counted vmcnt).
__global__ __launch_bounds__(512, 2) void gemm_bin(
    const float* __restrict__ X, const unsigned short* __restrict__ WbT,
    const float* __restrict__ bias, float* __restrict__ Z) {
  __shared__ __align__(16) unsigned short As[2][BM * BK];  // 64 KiB
  __shared__ __align__(16) unsigned short Bs[2][BN * BK];  // 64 KiB

  const int t   = (int)threadIdx.x;
  const int l   = t & 63;
  const int wid = t >> 6;
  const int wm  = wid >> 2;  // 0..1
  const int wn  = wid & 3;   // 0..3

  const int bid = (int)blockIdx.x;
  const int swz = (bid & 7) * 32 + (bid >> 3);  // bijective: 256 = 8*32
  const int m0  = (swz >> 2) * BM;
  const int n0  = (swz & 3) * BN;

  const int abase = (wm * 128 + (l & 15)) * BK;
  const int bbase = (wn * 64 + (l & 15)) * BK;
  const int axk0  = (((l >> 4) + 0) ^ (l & 7)) << 3;
  const int axk1  = (((l >> 4) + 4) ^ (l & 7)) << 3;

  // ---- A staging: thread owns granules {t, 512+t} (half1), {1024+t, 1536+t}
  // (half2); rows r = d>>3, g = t&7 fixed; all rows share (t>>3)&7 -> one XOR.
  const int rA = t >> 3, g = t & 7;
  const float* sA0 = X + (size_t)(m0 + rA) * K_DIM + g * 8;         // h1 row0
  const float* sA1 = X + (size_t)(m0 + 64 + rA) * K_DIM + g * 8;    // h1 row1
  const float* sB0 = X + (size_t)(m0 + 128 + rA) * K_DIM + g * 8;   // h2 row0
  const float* sB1 = X + (size_t)(m0 + 192 + rA) * K_DIM + g * 8;   // h2 row1
  const int adst = rA * BK + ((g ^ (rA & 7)) << 3);  // +4096 per 64 rows

  // ---- B staging: linear LDS dest, inverse-swizzled global source ----
  const unsigned short* b_src[4];
  int b_dst[4];
#pragma unroll
  for (int i = 0; i < 4; ++i) {
    const int c = i * 512 + t;
    const int n = c >> 3, gp = c & 7;
    b_src[i] = WbT + (size_t)(n0 + n) * K_DIM + (gp ^ (n & 7)) * 8;
    b_dst[i] = c * 8;
  }

  f32x4 acc[8][4] = {};
  f32x4 arA[2][2], arB[2][2];       // half1 / half2 staging regs (16 each)
  bf16x8 aF0[2][4], aF1[2][4];      // mh0 / mh1 fragment sets
  bf16x8 bR0[2][2], bR1[2][2];      // role-swapped per iter parity

#define SB0 __builtin_amdgcn_sched_barrier(0)
#define BAR do { SB0; __builtin_amdgcn_s_barrier(); SB0; } while (0)
#define WVM(N) do { asm volatile("s_waitcnt vmcnt(" #N ")" ::: "memory"); SB0; } while (0)
#define WLGC(N) do { asm volatile("s_waitcnt lgkmcnt(" #N ")" ::: "memory"); SB0; } while (0)
#define PRIO1 __builtin_amdgcn_s_setprio(1)
#define PRIO0 __builtin_amdgcn_s_setprio(0)

#define IA_H1(KT)                                                          \
  do { SB0;                                                                \
    arA[0][0] = *(const f32x4*)(sA0 + (KT));                               \
    arA[0][1] = *(const f32x4*)(sA0 + (KT) + 4);                           \
    arA[1][0] = *(const f32x4*)(sA1 + (KT));                               \
    arA[1][1] = *(const f32x4*)(sA1 + (KT) + 4); SB0;                      \
  } while (0)
#define IA_H2(KT)                                                          \
  do { SB0;                                                                \
    arB[0][0] = *(const f32x4*)(sB0 + (KT));                               \
    arB[0][1] = *(const f32x4*)(sB0 + (KT) + 4);                           \
    arB[1][0] = *(const f32x4*)(sB1 + (KT));                               \
    arB[1][1] = *(const f32x4*)(sB1 + (KT) + 4); SB0;                      \
  } while (0)
#define WR_H(BUF, AR, OFS)                                                 \
  do {                                                                     \
    _Pragma("unroll") for (int i = 0; i < 2; ++i) {                        \
      u16x8 v;                                                             \
      _Pragma("unroll") for (int j = 0; j < 4; ++j) {                      \
        v[j]     = (unsigned short)f2bf(AR[i][0][j]);                      \
        v[4 + j] = (unsigned short)f2bf(AR[i][1][j]);                      \
      }                                                                    \
      *(u16x8*)(&As[BUF][adst + (OFS) + i * 4096]) = v;                    \
    }                                                                      \
  } while (0)
#define ISSUE_B(KT, BUF)                                                   \
  do { SB0;                                                                \
    _Pragma("unroll") for (int i = 0; i < 4; ++i)                          \
      load_lds16(b_src[i] + (KT), &Bs[BUF][b_dst[i]]);                     \
    SB0;                                                                   \
  } while (0)
#define READ_AF(DST, MH, AB)                                               \
  do {                                                                     \
    _Pragma("unroll") for (int mi = 0; mi < 4; ++mi) {                     \
      DST[0][mi] = *(const bf16x8*)((AB) + abase + ((MH)*4 + mi) * 1024 + axk0); \
      DST[1][mi] = *(const bf16x8*)((AB) + abase + ((MH)*4 + mi) * 1024 + axk1); \
    }                                                                      \
  } while (0)
#define READ_BF(DST, NH, BB)                                               \
  do {                                                                     \
    _Pragma("unroll") for (int ni = 0; ni < 2; ++ni) {                     \
      DST[0][ni] = *(const bf16x8*)((BB) + bbase + ((NH)*2 + ni) * 1024 + axk0); \
      DST[1][ni] = *(const bf16x8*)((BB) + bbase + ((NH)*2 + ni) * 1024 + axk1); \
    }                                                                      \
  } while (0)
#define MFMA_Q(MH, NH, AFR, BFR)                                           \
  do { PRIO1;                                                              \
    _Pragma("unroll") for (int kk = 0; kk < 2; ++kk)                       \
      _Pragma("unroll") for (int mi = 0; mi < 4; ++mi)                     \
        _Pragma("unroll") for (int ni = 0; ni < 2; ++ni)                   \
          acc[(MH)*4 + mi][(NH)*2 + ni] =                                  \
              __builtin_amdgcn_mfma_f32_16x16x32_bf16(                     \
                  AFR[kk][mi], BFR[kk][ni], acc[(MH)*4 + mi][(NH)*2 + ni], \
                  0, 0, 0);                                                \
    PRIO0;                                                                 \
  } while (0)

  // One steady iteration; NA = q00/q10 B-frag set, NB = q01/q11 set.
  // lgkm in:[aF0:8, NA:4]  vm in:[A(t+1)a:4, B(t+1):4]
#define STEADY(TT, NA, NB)                                                 \
  do {                                                                     \
    const int buf = (TT) & 1;                                              \
    const unsigned short* Ab = As[buf];                                    \
    const unsigned short* Bb = Bs[buf];                                    \
    /* ph1 */                                                              \
    WVM(4);                         /* A(t+1) half1 regs arrived */        \
    WR_H(buf ^ 1, arA, 0);                                                 \
    IA_H1(((TT) + 1) * BK);         /* reuse: issue A(t+1) half2? no: */   \
    READ_BF(NB, 1, Bb);                                                    \
    BAR; WLGC(6);                   /* retire prev [aF0,NA]; wr2+NB stay */\
    MFMA_Q(0, 0, aF0, NA);                                                 \
    BAR;                                                                   \
    /* ph2 */                                                              \
    READ_AF(aF1, 1, Ab);                                                   \
    IA_H2(((TT) + 2) * BK);         /* A(t+2) half2 issue */               \
    BAR; WLGC(8);                   /* retire wr2+NB; aF1 stays */         \
    MFMA_Q(0, 1, aF0, NB);                                                 \
    BAR;                                                                   \
    /* ph3 */                                                              \
    WVM(4);                         /* retire B(t+1)+A(t+1)h2-src... */    \
    WR_H(buf ^ 1, arB, 8192);                                              \
    ISSUE_B(((TT) + 2) * BK, buf);                                         \
    BAR; WLGC(0);                   /* retire aF1 + wr2 (publish) */       \
    MFMA_Q(1, 1, aF1, NB);                                                 \
    BAR;                                                                   \
    /* ph4 */                                                              \
    READ_AF(aF0, 0, As[buf ^ 1]);                                          \
    READ_BF(NA, 0, Bs[buf ^ 1]);    /* next q00 frags -> freed NB role */  \
    BAR;                            /* no wait: q10 uses held regs */      \
    MFMA_Q(1, 0, aF1, NA##_hold);                                          \
    BAR;                                                                   \
  } while (0)

  // NOTE on STEADY: the "NA##_hold" trick is invalid C; instead the macro is
  // instantiated with explicit sets below via STEADY2 which keeps the held
  // NA set separate from the next-iter NA target (role swap).
#undef STEADY
#define STEADY2(TT, NAcur, NAnext)                                         \
  do {                                                                     \
    const int buf = (TT) & 1;                                              \
    const unsigned short* Ab = As[buf];                                    \
    const unsigned short* Bb = Bs[buf];                                    \
    /* ph1: in lgkm [aF0:8, NAcur:4]; vm [A(t+1)h1:4, B(t+1):4] */         \
    WVM(4);                                                                \
    WR_H(buf ^ 1, arA, 0);                                                 \
    IA_H2(((TT) + 1) * BK);         /* A(t+1) half2 -> arB */              \
    READ_BF(NAnext, 1, Bb);         /* NB role this iter */                \
    BAR; WLGC(6);                                                          \
    MFMA_Q(0, 0, aF0, NAcur);                                              \
    BAR;                                                                   \
    /* ph2 */                                                              \
    READ_AF(aF1, 1, Ab);                                                   \
    IA_H1(((TT) + 2) * BK);         /* A(t+2) half1 -> arA */              \
    BAR; WLGC(8);                                                          \
    MFMA_Q(0, 1, aF0, NAnext);                                             \
    BAR;                                                                   \
    /* ph3 */                                                              \
    WVM(4);                         /* retire B(t+1) + A(t+1)h2 */         \
    WR_H(buf ^ 1, arB, 8192);                                              \
    ISSUE_B(((TT) + 2) * BK, buf);                                         \
    BAR; WLGC(0);                                                          \
    MFMA_Q(1, 1, aF1, NAnext);                                             \
    BAR;                                                                   \
    /* ph4: read next-iter q00 frags into the freed NAcur set */           \
    READ_AF(aF0, 0, As[buf ^ 1]);                                          \
    READ_BF(NAcur, 0, Bs[buf ^ 1]);                                        \
    BAR;                                                                   \
    MFMA_Q(1, 0, aF1, NAcur);       /* WRONG set? no: see below */         \
    BAR;                                                                   \
  } while (0)
  // Correction: q10 must use the CURRENT NA (held), but ph4 overwrote NAcur
  // with next-iter frags. Swap: q10 consumes NAcur BEFORE the reads would
  // land? ds_reads are async; the MFMA after BAR with no lgkm wait may race
  // its own overwrite. Resolve by reading next-q00 frags into NAnext's
  // *other* role instead: at ph4, the set that is truly dead is NAnext? No —
  // NAnext (NB role) feeds q11 in ph3 and dies there. So ph4 reads into a
  // third alias = the set NOT used by q10. Since q10 uses NAcur, read into
  // NAnext — next iter's NA role IS NAnext. Correct pairing:
#undef STEADY2
#define STEADY3(TT, NAcur, NBcur)                                          \
  do {                                                                     \
    const int buf = (TT) & 1;                                              \
    const unsigned short* Ab = As[buf];                                    \
    const unsigned short* Bb = Bs[buf];                                    \
    /* ph1: in lgkm [aF0:8, NAcur:4]; vm [A(t+1)h1:4, B(t+1):4] */         \
    WVM(4);                                                                \
    WR_H(buf ^ 1, arA, 0);                                                 \
    IA_H2(((TT) + 1) * BK);                                                \
    READ_BF(NBcur, 1, Bb);                                                 \
    BAR; WLGC(6);                                                          \
    MFMA_Q(0, 0, aF0, NAcur);                                              \
    BAR;                                                                   \
    /* ph2 */                                                              \
    READ_AF(aF1, 1, Ab);                                                   \
    IA_H1(((TT) + 2) * BK);                                                \
    BAR; WLGC(8);                                                          \
    MFMA_Q(0, 1, aF0, NBcur);                                              \
    BAR;                                                                   \
    /* ph3 */                                                              \
    WVM(4);                                                                \
    WR_H(buf ^ 1, arB, 8192);                                              \
    ISSUE_B(((TT) + 2) * BK, buf);                                         \
    BAR; WLGC(0);                                                          \
    MFMA_Q(1, 1, aF1, NBcur);       /* NBcur dies here */                  \
    BAR;                                                                   \
    /* ph4: next-iter NA role = NBcur set (role swap) */                   \
    READ_AF(aF0, 0, As[buf ^ 1]);                                          \
    READ_BF(NBcur, 0, Bs[buf ^ 1]);                                        \
    BAR;                                                                   \
    MFMA_Q(1, 0, aF1, NAcur);       /* held since ph1 - safe */            \
    BAR;                                                                   \
  } while (0)

  // ---- prologue ----
  IA_H1(0); IA_H2(0);
  ISSUE_B(0, 0);
  WVM(8);            // A(0) half1 arrived
  WR_H(0, arA, 0);
  WVM(4);            // A(0) half2 arrived
  WR_H(0, arB, 8192);
  IA_H1(BK);         // A(1) half1
  ISSUE_B(BK, 1);    // B(1)
  WVM(8);            // retire B(0); [A(1)h1:4, B(1):4] remain
  WLGC(0);           // drain the 4 ds_writes
  BAR;
  READ_AF(aF0, 0, As[0]);
  READ_BF(bR0, 0, Bs[0]);   // lgkm [aF0:8, NA:4]

  // ---- steady: 62 iters as 31 role-swapped pairs ----
  for (int tp = 0; tp < (NT - 2) / 2; ++tp) {
    const int tt = 2 * tp;
    STEADY3(tt, bR0, bR1);
    STEADY3(tt + 1, bR1, bR0);
  }

  // ---- tail tile NT-2 (even parity: NA=bR0, NB=bR1), no new issues ----
  {
    const int buf = (NT - 2) & 1;            // = 0
    const unsigned short* Ab = As[buf];
    const unsigned short* Bb = Bs[buf];
    WVM(4);                                   // A(NT-1) h1
    WR_H(buf ^ 1, arA, 0);
    IA_H2((NT - 1) * BK);                     // A(NT-1) h2
    READ_BF(bR1, 1, Bb);
    BAR; WLGC(6);
    MFMA_Q(0, 0, aF0, bR0);
    BAR;
    READ_AF(aF1, 1, Ab);
    BAR; WLGC(8);
    MFMA_Q(0, 1, aF0, bR1);
    BAR;
    WVM(0);                                   // B(NT-1) + A(NT-1)h2 done
    WR_H(buf ^ 1, arB, 8192);
    BAR; WLGC(0);
    MFMA_Q(1, 1, aF1, bR1);
    BAR;
    READ_AF(aF0, 0, As[buf ^ 1]);
    READ_BF(bR1, 0, Bs[buf ^ 1]);             // next NA role = bR1
    BAR;
    MFMA_Q(1, 0, aF1, bR0);
    BAR;
  }
  // ---- last tile NT-1 (odd parity: NA=bR1, NB=bR0), straight-line ----
  {
    const int buf = (NT - 1) & 1;             // = 1
    const unsigned short* Ab = As[buf];
    const unsigned short* Bb = Bs[buf];
    WLGC(0);
    MFMA_Q(0, 0, aF0, bR1);
    READ_BF(bR0, 1, Bb);
    READ_AF(aF1, 1, Ab);
    WLGC(0);
    MFMA_Q(0, 1, aF0, bR0);
    MFMA_Q(1, 1, aF1, bR0);
    MFMA_Q(1, 0, aF1, bR1);
  }

  // ---- epilogue: + sign(bias); D frag: col = l&15, row = (l>>4)*4 + j ----
#pragma unroll
  for (int ni = 0; ni < 4; ++ni) {
    const int col = n0 + wn * 64 + ni * 16 + (l & 15);
    const float b  = bias[col];
    const float bs = (b > 0.f) ? 1.f : ((b < 0.f) ? -1.f : 0.f);
#pragma unroll
    for (int mi = 0; mi < 8; ++mi) {
      const int row = m0 + wm * 128 + mi * 16 + ((l >> 4) << 2);
#pragma unroll
      for (int j = 0; j < 4; ++j)
        Z[(size_t)(row + j) * N_DIM + col] = acc[mi][ni][j] + bs;
    }
  }
}

// ---------- slow-but-correct fallback (only if ws too small) ----------
__global__ __launch_bounds__(256) void naive_fb(
    const float* __restrict__ X, const float* __restrict__ W,
    const float* __restrict__ bias, float* __restrict__ Z) {
  const size_t id = (size_t)blockIdx.x * 256 + threadIdx.x;
  const int m = (int)(id >> 10), n = (int)(id & 1023);
  float acc = 0.f;
  for (int k = 0; k < K_DIM; ++k) {
    const float w = W[(size_t)k * N_DIM + n];
    const float s = (w > 0.f) ? 1.f : ((w < 0.f) ? -1.f : 0.f);
    acc += X[(size_t)m * K_DIM + k] * s;
  }
  const float b = bias[n];
  Z[id] = acc + ((b > 0.f) ? 1.f : ((b < 0.f) ? -1.f : 0.f));
}

extern "C" void kernel_launch(void* const* d_in, const int* in_sizes, int n_in,
                              void* d_out, int out_size, void* d_ws, size_t ws_size,
                              hipStream_t stream) {
  const float* X    = (const float*)d_in[0];
  const float* W    = (const float*)d_in[1];
  const float* bias = (const float*)d_in[2];
  float* Z = (float*)d_out;

  const size_t need = (size_t)N_DIM * K_DIM * sizeof(unsigned short);  // 8 MiB
  if (ws_size >= need) {
    unsigned short* WbT = (unsigned short*)d_ws;
    wsign_transpose<<<dim3((K_DIM / 64) * (N_DIM / 64)), dim3(256), 0, stream>>>(W, WbT);
    gemm_bin<<<dim3((M_DIM / BM) * (N_DIM / BN)), dim3(512), 0, stream>>>(X, WbT, bias, Z);
  } else {
    naive_fb<<<dim3((size_t)M_DIM * N_DIM / 256), dim3(256), 0, stream>>>(X, W, bias, Z);
  }
}

// Round 5
// 255.446 us; speedup vs baseline: 2.2619x; 2.2619x over previous
//
#include <hip/hip_runtime.h>

#define M_DIM 16384
#define N_DIM 1024
#define K_DIM 4096

#define BM 256
#define BN 256
#define BK 64
#define NT (K_DIM / BK)

typedef __attribute__((ext_vector_type(4))) float f32x4;
typedef __attribute__((ext_vector_type(8))) short bf16x8;
typedef __attribute__((ext_vector_type(8))) unsigned short u16x8;

static __device__ __forceinline__ short f2bf(float f) {
  union { __bf16 h; short s; } u;
  u.h = (__bf16)f;   // RNE; pairs pack into v_cvt_pk_bf16_f32
  return u.s;
}

static __device__ __forceinline__ void load_lds16(const void* g, void* l) {
  __builtin_amdgcn_global_load_lds(
      (const __attribute__((address_space(1))) void*)g,
      (__attribute__((address_space(3))) void*)l, 16, 0, 0);
}

// ---------- prepass 1: Xb = bf16(X), streaming ----------
__global__ __launch_bounds__(256) void xcvt(
    const float* __restrict__ X, unsigned short* __restrict__ Xb) {
  const size_t n8 = (size_t)M_DIM * K_DIM / 8;
  const size_t stride = (size_t)gridDim.x * 256;
  for (size_t i = (size_t)blockIdx.x * 256 + threadIdx.x; i < n8; i += stride) {
    const f32x4 v0 = *(const f32x4*)(X + i * 8);
    const f32x4 v1 = *(const f32x4*)(X + i * 8 + 4);
    u16x8 o;
#pragma unroll
    for (int j = 0; j < 4; ++j) {
      o[j]     = (unsigned short)f2bf(v0[j]);
      o[4 + j] = (unsigned short)f2bf(v1[j]);
    }
    *(u16x8*)(Xb + i * 8) = o;
  }
}

// ---------- prepass 2: WbT[n][k] = bf16(sign(W[k][n])) ----------
__global__ __launch_bounds__(256) void wsign_transpose(
    const float* __restrict__ W, unsigned short* __restrict__ WbT) {
  __shared__ unsigned short tile[64][72];
  const int t  = (int)threadIdx.x;
  const int k0 = (int)(blockIdx.x >> 4) * 64;
  const int n0 = (int)(blockIdx.x & 15) * 64;
#pragma unroll
  for (int p = 0; p < 4; ++p) {
    const int r = p * 16 + (t >> 4);
    const int c = (t & 15) * 4;
    const float* src = W + (size_t)(k0 + r) * N_DIM + n0 + c;
#pragma unroll
    for (int j = 0; j < 4; ++j) {
      const float w = src[j];
      tile[r][c + j] = (w > 0.f) ? (unsigned short)0x3F80u
                                 : ((w < 0.f) ? (unsigned short)0xBF80u
                                              : (unsigned short)0u);
    }
  }
  __syncthreads();
  const int n  = t >> 2;
  const int kg = (t & 3) * 16;
  u16x8 o0, o1;
#pragma unroll
  for (int j = 0; j < 8; ++j) o0[j] = tile[kg + j][n];
#pragma unroll
  for (int j = 0; j < 8; ++j) o1[j] = tile[kg + 8 + j][n];
  unsigned short* dst = WbT + (size_t)(n0 + n) * K_DIM + k0 + kg;
  *(u16x8*)dst       = o0;
  *(u16x8*)(dst + 8) = o1;
}

// ---------- main GEMM: A via LDS-DMA (bf16), B direct global->VGPR ----------
// 256x256 tile, BK=64, 8 waves (2Mx4N), per-wave 128x64.
// LDS = A only, 2 x 32 KiB double buffer. One barrier per K-tile.
__global__ __launch_bounds__(512, 2) void gemm_dma(
    const unsigned short* __restrict__ Xb, const unsigned short* __restrict__ WbT,
    const float* __restrict__ bias, float* __restrict__ Z) {
  __shared__ __align__(16) unsigned short As[2][BM * BK];  // 64 KiB

  const int t   = (int)threadIdx.x;
  const int l   = t & 63;
  const int wid = t >> 6;
  const int wm  = wid >> 2;  // 0..1
  const int wn  = wid & 3;   // 0..3

  const int bid = (int)blockIdx.x;
  const int swz = (bid & 7) * 32 + (bid >> 3);  // bijective: 256 = 8*32
  const int m0  = (swz >> 2) * BM;
  const int n0  = (swz & 3) * BN;

  // A fragment read offsets (XOR-swizzled, proven in R1)
  const int abase = (wm * 128 + (l & 15)) * BK;
  const int axk0  = (((l >> 4) + 0) ^ (l & 7)) << 3;
  const int axk1  = (((l >> 4) + 4) ^ (l & 7)) << 3;

  // A staging: 4 chunks/thread; linear LDS dest, inverse-swizzled source
  const unsigned short* a_src[4];
  int a_dst[4];
#pragma unroll
  for (int i = 0; i < 4; ++i) {
    const int c = i * 512 + t;
    const int r = c >> 3, g = c & 7;
    a_src[i] = Xb + (size_t)(m0 + r) * K_DIM + (g ^ (r & 7)) * 8;
    a_dst[i] = c * 8;
  }
  // B fragment per-lane base pointers (one per ni); 16B contiguous loads
  const unsigned short* bp[4];
#pragma unroll
  for (int ni = 0; ni < 4; ++ni)
    bp[ni] = WbT + (size_t)(n0 + wn * 64 + ni * 16 + (l & 15)) * K_DIM +
             (l >> 4) * 8;

  f32x4 acc[8][4] = {};
  bf16x8 aF0[2][4], aF1[2][4];  // mh0 / mh1 fragment sets
  bf16x8 PB0[2][2], PB1[2][2];  // B frags ni{0,1} / ni{2,3}

#define SB0 __builtin_amdgcn_sched_barrier(0)
#define BAR do { SB0; __builtin_amdgcn_s_barrier(); SB0; } while (0)
#define WVM(N) do { asm volatile("s_waitcnt vmcnt(" #N ")" ::: "memory"); SB0; } while (0)
#define WLG0 do { asm volatile("s_waitcnt lgkmcnt(0)" ::: "memory"); SB0; } while (0)

#define DMA_A(KT, BUF)                                                     \
  do { SB0;                                                                \
    _Pragma("unroll") for (int i = 0; i < 4; ++i)                          \
      load_lds16(a_src[i] + (KT), &As[BUF][a_dst[i]]);                     \
    SB0;                                                                   \
  } while (0)
#define LD_PB(SET, NIB, KT)                                                \
  do { SB0;                                                                \
    _Pragma("unroll") for (int kk = 0; kk < 2; ++kk)                       \
      _Pragma("unroll") for (int nj = 0; nj < 2; ++nj)                     \
        SET[kk][nj] = *(const bf16x8*)(bp[(NIB) + nj] + (KT) + kk * 32);   \
    SB0;                                                                   \
  } while (0)
#define RD_A(DST, MH, AB)                                                  \
  do { SB0;                                                                \
    _Pragma("unroll") for (int mi = 0; mi < 4; ++mi) {                     \
      DST[0][mi] = *(const bf16x8*)((AB) + abase + ((MH)*4 + mi) * 1024 + axk0); \
      DST[1][mi] = *(const bf16x8*)((AB) + abase + ((MH)*4 + mi) * 1024 + axk1); \
    } SB0;                                                                 \
  } while (0)
#define Q(MH, NH, AFR, BSET)                                               \
  do { __builtin_amdgcn_s_setprio(1);                                      \
    _Pragma("unroll") for (int kk = 0; kk < 2; ++kk)                       \
      _Pragma("unroll") for (int mi = 0; mi < 4; ++mi)                     \
        _Pragma("unroll") for (int nj = 0; nj < 2; ++nj)                   \
          acc[(MH)*4 + mi][(NH)*2 + nj] =                                  \
              __builtin_amdgcn_mfma_f32_16x16x32_bf16(                     \
                  AFR[kk][mi], BSET[kk][nj], acc[(MH)*4 + mi][(NH)*2 + nj],\
                  0, 0, 0);                                                \
    __builtin_amdgcn_s_setprio(0);                                         \
  } while (0)

  // ---- prologue: queue = [A(0):4, PB1(0):4, PB0(0):4] ----
  DMA_A(0, 0);
  LD_PB(PB1, 2, 0);
  LD_PB(PB0, 0, 0);
  WVM(8);        // A(0) DMA complete
  BAR;

  // ---- steady: tt = 0..NT-2 ----
  for (int tt = 0; tt < NT - 1; ++tt) {
    const unsigned short* Ab = As[tt & 1];
    const int ktn = (tt + 1) * BK;
    // ph1: issue next A DMA; read mh0 frags
    DMA_A(ktn, (tt + 1) & 1);
    RD_A(aF0, 0, Ab);
    // ph2: PB(t) arrived; q00; read mh1 frags
    WVM(4);      // queue [PB1(t),PB0(t),A(t+1)] -> retire both PB sets
    WLG0;        // aF0 ready
    Q(0, 0, aF0, PB0);
    RD_A(aF1, 1, Ab);
    // ph3: q01, q11 (PB1(t) dies), then issue PB1(t+1)
    Q(0, 1, aF0, PB1);
    WLG0;        // aF1 ready
    Q(1, 1, aF1, PB1);
    LD_PB(PB1, 2, ktn);
    // ph4: q10 (PB0(t) dies), issue PB0(t+1); A(t+1) done; publish
    Q(1, 0, aF1, PB0);
    LD_PB(PB0, 0, ktn);
    WVM(8);      // queue [A(t+1),PB1(t+1),PB0(t+1)] -> retire A(t+1)
    BAR;
  }

  // ---- tail tile NT-1 ----
  {
    const unsigned short* Ab = As[(NT - 1) & 1];
    RD_A(aF0, 0, Ab);
    WVM(0);      // PB1,PB0 of last tile arrived
    WLG0;
    Q(0, 0, aF0, PB0);
    RD_A(aF1, 1, Ab);
    Q(0, 1, aF0, PB1);
    WLG0;
    Q(1, 1, aF1, PB1);
    Q(1, 0, aF1, PB0);
  }

  // ---- epilogue: + sign(bias); D frag: col = l&15, row = (l>>4)*4 + j ----
#pragma unroll
  for (int ni = 0; ni < 4; ++ni) {
    const int col = n0 + wn * 64 + ni * 16 + (l & 15);
    const float b  = bias[col];
    const float bs = (b > 0.f) ? 1.f : ((b < 0.f) ? -1.f : 0.f);
#pragma unroll
    for (int mi = 0; mi < 8; ++mi) {
      const int row = m0 + wm * 128 + mi * 16 + ((l >> 4) << 2);
#pragma unroll
      for (int j = 0; j < 4; ++j)
        Z[(size_t)(row + j) * N_DIM + col] = acc[mi][ni][j] + bs;
    }
  }
#undef SB0
#undef BAR
#undef WVM
#undef WLG0
#undef DMA_A
#undef LD_PB
#undef RD_A
#undef Q
}

// ---------- fallback GEMM (R1, proven 213us): fused fp32-A, needs 8 MiB ws ----
__global__ __launch_bounds__(512, 2) void gemm_fused(
    const float* __restrict__ X, const unsigned short* __restrict__ WbT,
    const float* __restrict__ bias, float* __restrict__ Z) {
  __shared__ __align__(16) unsigned short As[2][BM * BK];
  __shared__ __align__(16) unsigned short Bs[2][BN * BK];

  const int t   = (int)threadIdx.x;
  const int l   = t & 63;
  const int wid = t >> 6;
  const int wm  = wid >> 2;
  const int wn  = wid & 3;

  const int bid = (int)blockIdx.x;
  const int swz = (bid & 7) * 32 + (bid >> 3);
  const int m0  = (swz >> 2) * BM;
  const int n0  = (swz & 3) * BN;

  const int abase = (wm * 128 + (l & 15)) * BK;
  const int bbase = (wn * 64 + (l & 15)) * BK;
  const int axk0  = (((l >> 4) + 0) ^ (l & 7)) << 3;
  const int axk1  = (((l >> 4) + 4) ^ (l & 7)) << 3;

  const float* a_src[4];
  int a_dst[4];
#pragma unroll
  for (int i = 0; i < 4; ++i) {
    const int d = i * 512 + t;
    const int row = d >> 3, g = d & 7;
    a_src[i] = X + (size_t)(m0 + row) * K_DIM + g * 8;
    a_dst[i] = row * BK + ((g ^ (row & 7)) << 3);
  }
  const unsigned short* b_src[4];
  int b_dst[4];
#pragma unroll
  for (int i = 0; i < 4; ++i) {
    const int c = i * 512 + t;
    const int n = c >> 3, gp = c & 7;
    b_src[i] = WbT + (size_t)(n0 + n) * K_DIM + (gp ^ (n & 7)) * 8;
    b_dst[i] = c * 8;
  }

  f32x4 acc[8][4] = {};
  f32x4 areg[4][2];

#define STAGE_A_LOAD(KT)                                                  \
  {                                                                       \
    _Pragma("unroll") for (int i = 0; i < 4; ++i) {                       \
      areg[i][0] = *(const f32x4*)(a_src[i] + (KT));                      \
      areg[i][1] = *(const f32x4*)(a_src[i] + (KT) + 4);                  \
    }                                                                     \
  }
#define STAGE_A_WRITE(BUF)                                                \
  {                                                                       \
    _Pragma("unroll") for (int i = 0; i < 4; ++i) {                       \
      u16x8 v;                                                            \
      _Pragma("unroll") for (int j = 0; j < 4; ++j) {                     \
        v[j]     = (unsigned short)f2bf(areg[i][0][j]);                   \
        v[4 + j] = (unsigned short)f2bf(areg[i][1][j]);                   \
      }                                                                   \
      *(u16x8*)(&As[BUF][a_dst[i]]) = v;                                  \
    }                                                                     \
  }
#define STAGE_B(KT, BUF)                                                  \
  {                                                                       \
    _Pragma("unroll") for (int i = 0; i < 4; ++i)                         \
      load_lds16(b_src[i] + (KT), &Bs[BUF][b_dst[i]]);                    \
  }
#define COMPUTE(CUR)                                                      \
  {                                                                       \
    const unsigned short* Ab = As[CUR];                                   \
    const unsigned short* Bb = Bs[CUR];                                   \
    _Pragma("unroll") for (int kk = 0; kk < 2; ++kk) {                    \
      const int axk = kk ? axk1 : axk0;                                   \
      bf16x8 bf[4];                                                       \
      _Pragma("unroll") for (int ni = 0; ni < 4; ++ni)                    \
        bf[ni] = *(const bf16x8*)(Bb + bbase + ni * 1024 + axk);          \
      _Pragma("unroll") for (int mi = 0; mi < 8; ++mi) {                  \
        const bf16x8 af = *(const bf16x8*)(Ab + abase + mi * 1024 + axk); \
        _Pragma("unroll") for (int ni = 0; ni < 4; ++ni)                  \
          acc[mi][ni] = __builtin_amdgcn_mfma_f32_16x16x32_bf16(          \
              af, bf[ni], acc[mi][ni], 0, 0, 0);                          \
      }                                                                   \
    }                                                                     \
  }

  STAGE_A_LOAD(0);
  STAGE_B(0, 0);
  STAGE_A_WRITE(0);
  __syncthreads();

  int cur = 0;
  for (int tt = 0; tt < NT - 1; ++tt) {
    const int ktn = (tt + 1) * BK;
    STAGE_A_LOAD(ktn);
    STAGE_B(ktn, cur ^ 1);
    COMPUTE(cur);
    STAGE_A_WRITE(cur ^ 1);
    __syncthreads();
    cur ^= 1;
  }
  COMPUTE(cur);

#pragma unroll
  for (int ni = 0; ni < 4; ++ni) {
    const int col = n0 + wn * 64 + ni * 16 + (l & 15);
    const float b  = bias[col];
    const float bs = (b > 0.f) ? 1.f : ((b < 0.f) ? -1.f : 0.f);
#pragma unroll
    for (int mi = 0; mi < 8; ++mi) {
      const int row = m0 + wm * 128 + mi * 16 + ((l >> 4) << 2);
#pragma unroll
      for (int j = 0; j < 4; ++j)
        Z[(size_t)(row + j) * N_DIM + col] = acc[mi][ni][j] + bs;
    }
  }
#undef STAGE_A_LOAD
#undef STAGE_A_WRITE
#undef STAGE_B
#undef COMPUTE
}

// ---------- slow-but-correct fallback ----------
__global__ __launch_bounds__(256) void naive_fb(
    const float* __restrict__ X, const float* __restrict__ W,
    const float* __restrict__ bias, float* __restrict__ Z) {
  const size_t id = (size_t)blockIdx.x * 256 + threadIdx.x;
  const int m = (int)(id >> 10), n = (int)(id & 1023);
  float acc = 0.f;
  for (int k = 0; k < K_DIM; ++k) {
    const float w = W[(size_t)k * N_DIM + n];
    const float s = (w > 0.f) ? 1.f : ((w < 0.f) ? -1.f : 0.f);
    acc += X[(size_t)m * K_DIM + k] * s;
  }
  const float b = bias[n];
  Z[id] = acc + ((b > 0.f) ? 1.f : ((b < 0.f) ? -1.f : 0.f));
}

extern "C" void kernel_launch(void* const* d_in, const int* in_sizes, int n_in,
                              void* d_out, int out_size, void* d_ws, size_t ws_size,
                              hipStream_t stream) {
  const float* X    = (const float*)d_in[0];
  const float* W    = (const float*)d_in[1];
  const float* bias = (const float*)d_in[2];
  float* Z = (float*)d_out;

  const size_t needW = (size_t)N_DIM * K_DIM * sizeof(unsigned short);  // 8 MiB
  const size_t needX = (size_t)M_DIM * K_DIM * sizeof(unsigned short);  // 128 MiB
  if (ws_size >= needW + needX) {
    unsigned short* WbT = (unsigned short*)d_ws;
    unsigned short* Xb  = (unsigned short*)((char*)d_ws + needW);
    xcvt<<<dim3(2048), dim3(256), 0, stream>>>(X, Xb);
    wsign_transpose<<<dim3((K_DIM / 64) * (N_DIM / 64)), dim3(256), 0, stream>>>(W, WbT);
    gemm_dma<<<dim3((M_DIM / BM) * (N_DIM / BN)), dim3(512), 0, stream>>>(Xb, WbT, bias, Z);
  } else if (ws_size >= needW) {
    unsigned short* WbT = (unsigned short*)d_ws;
    wsign_transpose<<<dim3((K_DIM / 64) * (N_DIM / 64)), dim3(256), 0, stream>>>(W, WbT);
    gemm_fused<<<dim3((M_DIM / BM) * (N_DIM / BN)), dim3(512), 0, stream>>>(X, WbT, bias, Z);
  } else {
    naive_fb<<<dim3((size_t)M_DIM * N_DIM / 256), dim3(256), 0, stream>>>(X, W, bias, Z);
  }
}

// Round 6
// 202.548 us; speedup vs baseline: 2.8526x; 1.2612x over previous
//
#include <hip/hip_runtime.h>

#define M_DIM 16384
#define N_DIM 1024
#define K_DIM 4096

#define BM 256
#define BN 256
#define BK 64
#define NT (K_DIM / BK)

typedef __attribute__((ext_vector_type(4))) float f32x4;
typedef __attribute__((ext_vector_type(8))) short bf16x8;
typedef __attribute__((ext_vector_type(8))) unsigned short u16x8;

static __device__ __forceinline__ short f2bf(float f) {
  union { __bf16 h; short s; } u;
  u.h = (__bf16)f;   // RNE; pairs pack into v_cvt_pk_bf16_f32
  return u.s;
}

static __device__ __forceinline__ void load_lds16(const void* g, void* l) {
  __builtin_amdgcn_global_load_lds(
      (const __attribute__((address_space(1))) void*)g,
      (__attribute__((address_space(3))) void*)l, 16, 0, 0);
}

// ---------- prepass: WbT[n][k] = bf16(sign(W[k][n])) ----------
__global__ __launch_bounds__(256) void wsign_transpose(
    const float* __restrict__ W, unsigned short* __restrict__ WbT) {
  __shared__ unsigned short tile[64][72];
  const int t  = (int)threadIdx.x;
  const int k0 = (int)(blockIdx.x >> 4) * 64;
  const int n0 = (int)(blockIdx.x & 15) * 64;
#pragma unroll
  for (int p = 0; p < 4; ++p) {
    const int r = p * 16 + (t >> 4);
    const int c = (t & 15) * 4;
    const float* src = W + (size_t)(k0 + r) * N_DIM + n0 + c;
#pragma unroll
    for (int j = 0; j < 4; ++j) {
      const float w = src[j];
      tile[r][c + j] = (w > 0.f) ? (unsigned short)0x3F80u
                                 : ((w < 0.f) ? (unsigned short)0xBF80u
                                              : (unsigned short)0u);
    }
  }
  __syncthreads();
  const int n  = t >> 2;
  const int kg = (t & 3) * 16;
  u16x8 o0, o1;
#pragma unroll
  for (int j = 0; j < 8; ++j) o0[j] = tile[kg + j][n];
#pragma unroll
  for (int j = 0; j < 8; ++j) o1[j] = tile[kg + 8 + j][n];
  unsigned short* dst = WbT + (size_t)(n0 + n) * K_DIM + k0 + kg;
  *(u16x8*)dst       = o0;
  *(u16x8*)(dst + 8) = o1;
}

// ---------- main GEMM: 256x256, BK=64, 8 waves, m201-style 4-phase ----------
// Each phase: {ds_read subtile || stage-issue} -> BAR -> lgkm(0) -> 16 MFMA
// (setprio) -> BAR. A: fused fp32->bf16 reg-staging (no Xb prepass).
// B: global_load_lds w16 with pre-swizzled source. Counted vmcnt mid-loop.
__global__ __launch_bounds__(512, 2) void gemm_8ph(
    const float* __restrict__ X, const unsigned short* __restrict__ WbT,
    const float* __restrict__ bias, float* __restrict__ Z) {
  __shared__ __align__(16) unsigned short As[2][BM * BK];  // 64 KiB
  __shared__ __align__(16) unsigned short Bs[2][BN * BK];  // 64 KiB

  const int t   = (int)threadIdx.x;
  const int l   = t & 63;
  const int wid = t >> 6;
  const int wm  = wid >> 2;  // 0..1
  const int wn  = wid & 3;   // 0..3

  const int bid = (int)blockIdx.x;
  const int swz = (bid & 7) * 32 + (bid >> 3);  // bijective: 256 = 8*32
  const int m0  = (swz >> 2) * BM;
  const int n0  = (swz & 3) * BN;

  // fragment read offsets (XOR-swizzled; proven R1/R2/R5)
  const int abase = (wm * 128 + (l & 15)) * BK;
  const int bbase = (wn * 64 + (l & 15)) * BK;
  const int axk0  = (((l >> 4) + 0) ^ (l & 7)) << 3;
  const int axk1  = (((l >> 4) + 4) ^ (l & 7)) << 3;

  // A staging (fused cvt): thread owns rows {i*64 + t>>3}, k-granule t&7
  const float* sA[4];
#pragma unroll
  for (int i = 0; i < 4; ++i)
    sA[i] = X + (size_t)(m0 + i * 64 + (t >> 3)) * K_DIM + (t & 7) * 8;
  const int adst = (t >> 3) * BK + (((t & 7) ^ ((t >> 3) & 7)) << 3);

  // B staging: linear LDS dest, inverse-swizzled global source
  const unsigned short* b_src[4];
  int b_dst[4];
#pragma unroll
  for (int i = 0; i < 4; ++i) {
    const int c = i * 512 + t;
    const int n = c >> 3, gp = c & 7;
    b_src[i] = WbT + (size_t)(n0 + n) * K_DIM + (gp ^ (n & 7)) * 8;
    b_dst[i] = c * 8;
  }

  f32x4 acc[8][4] = {};
  f32x4 ar[2][2];               // one A-half staging set (16 VGPR)
  bf16x8 aF[2][4];              // one mh fragment set (32 VGPR)
  bf16x8 bF0[2][2], bF1[2][2];  // nh0 / nh1 fragment sets (16+16)

#define SB0 __builtin_amdgcn_sched_barrier(0)
#define BAR do { SB0; __builtin_amdgcn_s_barrier(); SB0; } while (0)
#define WVM(N) do { asm volatile("s_waitcnt vmcnt(" #N ")" ::: "memory"); SB0; } while (0)
#define WLG0 do { asm volatile("s_waitcnt lgkmcnt(0)" ::: "memory"); SB0; } while (0)

#define LD_AH(H, KT)                                                       \
  do { SB0;                                                                \
    ar[0][0] = *(const f32x4*)(sA[2 * (H)] + (KT));                        \
    ar[0][1] = *(const f32x4*)(sA[2 * (H)] + (KT) + 4);                    \
    ar[1][0] = *(const f32x4*)(sA[2 * (H) + 1] + (KT));                    \
    ar[1][1] = *(const f32x4*)(sA[2 * (H) + 1] + (KT) + 4); SB0;           \
  } while (0)
#define WR_AH(H, BUF)                                                      \
  do {                                                                     \
    _Pragma("unroll") for (int j = 0; j < 2; ++j) {                        \
      u16x8 v;                                                             \
      _Pragma("unroll") for (int q = 0; q < 4; ++q) {                      \
        v[q]     = (unsigned short)f2bf(ar[j][0][q]);                      \
        v[4 + q] = (unsigned short)f2bf(ar[j][1][q]);                      \
      }                                                                    \
      *(u16x8*)(&As[BUF][adst + (2 * (H) + j) * 4096]) = v;                \
    }                                                                      \
  } while (0)
#define DMA_B2(KT, BUF, I0)                                                \
  do { SB0;                                                                \
    _Pragma("unroll") for (int i = (I0); i < (I0) + 2; ++i)                \
      load_lds16(b_src[i] + (KT), &Bs[BUF][b_dst[i]]);                     \
    SB0;                                                                   \
  } while (0)
#define RD_A(MH, AB)                                                       \
  do { SB0;                                                                \
    _Pragma("unroll") for (int mi = 0; mi < 4; ++mi) {                     \
      aF[0][mi] = *(const bf16x8*)((AB) + abase + ((MH)*4 + mi) * 1024 + axk0); \
      aF[1][mi] = *(const bf16x8*)((AB) + abase + ((MH)*4 + mi) * 1024 + axk1); \
    } SB0;                                                                 \
  } while (0)
#define RD_B(DST, NH, BB)                                                  \
  do { SB0;                                                                \
    _Pragma("unroll") for (int nj = 0; nj < 2; ++nj) {                     \
      DST[0][nj] = *(const bf16x8*)((BB) + bbase + ((NH)*2 + nj) * 1024 + axk0); \
      DST[1][nj] = *(const bf16x8*)((BB) + bbase + ((NH)*2 + nj) * 1024 + axk1); \
    } SB0;                                                                 \
  } while (0)
#define Q(MH, NH, BF)                                                      \
  do { __builtin_amdgcn_s_setprio(1);                                      \
    _Pragma("unroll") for (int kk = 0; kk < 2; ++kk)                       \
      _Pragma("unroll") for (int mi = 0; mi < 4; ++mi)                     \
        _Pragma("unroll") for (int nj = 0; nj < 2; ++nj)                   \
          acc[(MH)*4 + mi][(NH)*2 + nj] =                                  \
              __builtin_amdgcn_mfma_f32_16x16x32_bf16(                     \
                  aF[kk][mi], BF[kk][nj], acc[(MH)*4 + mi][(NH)*2 + nj],   \
                  0, 0, 0);                                                \
    __builtin_amdgcn_s_setprio(0);                                         \
  } while (0)

  // ---- prologue: stage tile 0 (serialized; not perf-critical) ----
  LD_AH(0, 0); WVM(0); WR_AH(0, 0);
  LD_AH(1, 0); WVM(0); WR_AH(1, 0);
  DMA_B2(0, 0, 0); DMA_B2(0, 0, 2);
  WVM(0); WLG0;
  BAR;

  // ---- steady: compute tile tt, stage tile tt+1 ----
  for (int tt = 0; tt < NT - 1; ++tt) {
    const int cur = tt & 1, nxt = cur ^ 1;
    const unsigned short* Ab = As[cur];
    const unsigned short* Bb = Bs[cur];
    const int ktn = (tt + 1) * BK;
    // P1: frags mh0+nh0; issue A(t+1) h1 fp32 loads
    RD_A(0, Ab);
    RD_B(bF0, 0, Bb);
    LD_AH(0, ktn);                 // vm: [Ah1:4]
    BAR; WLG0;
    Q(0, 0, bF0);
    BAR;
    // P2: frags nh1; issue B(t+1) dma h0; retire Ah1; cvt+write h1
    RD_B(bF1, 1, Bb);
    DMA_B2(ktn, nxt, 0);           // vm: [Ah1:4, Bd0:2]
    WVM(2);                        // Ah1 arrived; Bd0 stays in flight
    WR_AH(0, nxt);
    BAR; WLG0;
    Q(0, 1, bF1);
    BAR;
    // P3: frags mh1; issue A(t+1) h2 + B(t+1) dma h1
    RD_A(1, Ab);
    LD_AH(1, ktn);                 // vm: [Bd0:2, Ah2:4]
    DMA_B2(ktn, nxt, 2);           // vm: [Bd0:2, Ah2:4, Bd1:2]
    BAR; WLG0;
    Q(1, 1, bF1);
    BAR;
    // P4: retire everything (B must land before publish); write h2; q10
    WVM(0);
    WR_AH(1, nxt);
    Q(1, 0, bF0);
    WLG0;                          // drain h2 ds_writes
    BAR;                           // publish tile t+1
  }

  // ---- tail: tile NT-1 (buf 1), pure compute ----
  {
    const unsigned short* Ab = As[(NT - 1) & 1];
    const unsigned short* Bb = Bs[(NT - 1) & 1];
    RD_A(0, Ab);
    RD_B(bF0, 0, Bb);
    WLG0;
    Q(0, 0, bF0);
    RD_B(bF1, 1, Bb);
    WLG0;
    Q(0, 1, bF1);
    RD_A(1, Ab);
    WLG0;
    Q(1, 1, bF1);
    Q(1, 0, bF0);
  }

  // ---- epilogue: + sign(bias); D frag: col = l&15, row = (l>>4)*4 + j ----
#pragma unroll
  for (int ni = 0; ni < 4; ++ni) {
    const int col = n0 + wn * 64 + ni * 16 + (l & 15);
    const float b  = bias[col];
    const float bs = (b > 0.f) ? 1.f : ((b < 0.f) ? -1.f : 0.f);
#pragma unroll
    for (int mi = 0; mi < 8; ++mi) {
      const int row = m0 + wm * 128 + mi * 16 + ((l >> 4) << 2);
#pragma unroll
      for (int j = 0; j < 4; ++j)
        Z[(size_t)(row + j) * N_DIM + col] = acc[mi][ni][j] + bs;
    }
  }
#undef SB0
#undef BAR
#undef WVM
#undef WLG0
#undef LD_AH
#undef WR_AH
#undef DMA_B2
#undef RD_A
#undef RD_B
#undef Q
}

// ---------- slow-but-correct fallback ----------
__global__ __launch_bounds__(256) void naive_fb(
    const float* __restrict__ X, const float* __restrict__ W,
    const float* __restrict__ bias, float* __restrict__ Z) {
  const size_t id = (size_t)blockIdx.x * 256 + threadIdx.x;
  const int m = (int)(id >> 10), n = (int)(id & 1023);
  float acc = 0.f;
  for (int k = 0; k < K_DIM; ++k) {
    const float w = W[(size_t)k * N_DIM + n];
    const float s = (w > 0.f) ? 1.f : ((w < 0.f) ? -1.f : 0.f);
    acc += X[(size_t)m * K_DIM + k] * s;
  }
  const float b = bias[n];
  Z[id] = acc + ((b > 0.f) ? 1.f : ((b < 0.f) ? -1.f : 0.f));
}

extern "C" void kernel_launch(void* const* d_in, const int* in_sizes, int n_in,
                              void* d_out, int out_size, void* d_ws, size_t ws_size,
                              hipStream_t stream) {
  const float* X    = (const float*)d_in[0];
  const float* W    = (const float*)d_in[1];
  const float* bias = (const float*)d_in[2];
  float* Z = (float*)d_out;

  const size_t needW = (size_t)N_DIM * K_DIM * sizeof(unsigned short);  // 8 MiB
  if (ws_size >= needW) {
    unsigned short* WbT = (unsigned short*)d_ws;
    wsign_transpose<<<dim3((K_DIM / 64) * (N_DIM / 64)), dim3(256), 0, stream>>>(W, WbT);
    gemm_8ph<<<dim3((M_DIM / BM) * (N_DIM / BN)), dim3(512), 0, stream>>>(X, WbT, bias, Z);
  } else {
    naive_fb<<<dim3((size_t)M_DIM * N_DIM / 256), dim3(256), 0, stream>>>(X, W, bias, Z);
  }
}

// Round 7
// 187.061 us; speedup vs baseline: 3.0888x; 1.0828x over previous
//
#include <hip/hip_runtime.h>

#define M_DIM 16384
#define N_DIM 1024
#define K_DIM 4096

#define BM 256
#define BN 256
#define BK 64
#define NT (K_DIM / BK)

typedef __attribute__((ext_vector_type(4))) float f32x4;
typedef __attribute__((ext_vector_type(8))) short bf16x8;
typedef __attribute__((ext_vector_type(8))) unsigned short u16x8;

static __device__ __forceinline__ short f2bf(float f) {
  union { __bf16 h; short s; } u;
  u.h = (__bf16)f;   // RNE; pairs pack into v_cvt_pk_bf16_f32
  return u.s;
}

static __device__ __forceinline__ void load_lds16(const void* g, void* l) {
  __builtin_amdgcn_global_load_lds(
      (const __attribute__((address_space(1))) void*)g,
      (__attribute__((address_space(3))) void*)l, 16, 0, 0);
}

// ---------- prepass: WbT[n][k] = bf16(sign(W[k][n])) ----------
__global__ __launch_bounds__(256) void wsign_transpose(
    const float* __restrict__ W, unsigned short* __restrict__ WbT) {
  __shared__ unsigned short tile[64][72];
  const int t  = (int)threadIdx.x;
  const int k0 = (int)(blockIdx.x >> 4) * 64;
  const int n0 = (int)(blockIdx.x & 15) * 64;
#pragma unroll
  for (int p = 0; p < 4; ++p) {
    const int r = p * 16 + (t >> 4);
    const int c = (t & 15) * 4;
    const float* src = W + (size_t)(k0 + r) * N_DIM + n0 + c;
#pragma unroll
    for (int j = 0; j < 4; ++j) {
      const float w = src[j];
      tile[r][c + j] = (w > 0.f) ? (unsigned short)0x3F80u
                                 : ((w < 0.f) ? (unsigned short)0xBF80u
                                              : (unsigned short)0u);
    }
  }
  __syncthreads();
  const int n  = t >> 2;
  const int kg = (t & 3) * 16;
  u16x8 o0, o1;
#pragma unroll
  for (int j = 0; j < 8; ++j) o0[j] = tile[kg + j][n];
#pragma unroll
  for (int j = 0; j < 8; ++j) o1[j] = tile[kg + 8 + j][n];
  unsigned short* dst = WbT + (size_t)(n0 + n) * K_DIM + k0 + kg;
  *(u16x8*)dst       = o0;
  *(u16x8*)(dst + 8) = o1;
}

// ---------- main GEMM: 256x256, BK=64, 8 waves, 4-phase, 2-tiles-ahead ----------
// Steady tile t: compute buf c=t&1; write A(t+1) regs->buf n; DMA B(t+1)->n;
// issue A(t+2) global loads. vmcnt counted 8/4/2 -- NEVER drained in loop.
__global__ __launch_bounds__(512, 2) void gemm_p4(
    const float* __restrict__ X, const unsigned short* __restrict__ WbT,
    const float* __restrict__ bias, float* __restrict__ Z) {
  __shared__ __align__(16) unsigned short As[2][BM * BK];  // 64 KiB
  __shared__ __align__(16) unsigned short Bs[2][BN * BK];  // 64 KiB

  const int t   = (int)threadIdx.x;
  const int l   = t & 63;
  const int wid = t >> 6;
  const int wm  = wid >> 2;  // 0..1
  const int wn  = wid & 3;   // 0..3

  const int bid = (int)blockIdx.x;
  const int swz = (bid & 7) * 32 + (bid >> 3);  // bijective: 256 = 8*32
  const int m0  = (swz >> 2) * BM;
  const int n0  = (swz & 3) * BN;

  // fragment read offsets (XOR-swizzled; verified R1..R6)
  const int abase = (wm * 128 + (l & 15)) * BK;
  const int bbase = (wn * 64 + (l & 15)) * BK;
  const int axk0  = (((l >> 4) + 0) ^ (l & 7)) << 3;
  const int axk1  = (((l >> 4) + 4) ^ (l & 7)) << 3;

  // A staging: thread owns rows {i*64 + t>>3}, k-granule t&7
  const float* sA0 = X + (size_t)(m0 +   0 + (t >> 3)) * K_DIM + (t & 7) * 8;
  const float* sA1 = X + (size_t)(m0 +  64 + (t >> 3)) * K_DIM + (t & 7) * 8;
  const float* sA2 = X + (size_t)(m0 + 128 + (t >> 3)) * K_DIM + (t & 7) * 8;
  const float* sA3 = X + (size_t)(m0 + 192 + (t >> 3)) * K_DIM + (t & 7) * 8;
  const int adst = (t >> 3) * BK + (((t & 7) ^ ((t >> 3) & 7)) << 3);

  // B staging: linear LDS dest, inverse-swizzled global source
  const unsigned short* b_src[4];
  int b_dst[4];
#pragma unroll
  for (int i = 0; i < 4; ++i) {
    const int c = i * 512 + t;
    const int n = c >> 3, gp = c & 7;
    b_src[i] = WbT + (size_t)(n0 + n) * K_DIM + (gp ^ (n & 7)) * 8;
    b_dst[i] = c * 8;
  }

  f32x4 acc[8][4] = {};
  f32x4 ar1[2][2], ar2[2][2];   // A(t+1) half1 / half2 staging (32 VGPR)
  bf16x8 aF[2][4];              // current mh fragment set (32 VGPR)
  bf16x8 bF0[2][2], bF1[2][2];  // nh0 / nh1 fragment sets (16+16)

#define SB0 __builtin_amdgcn_sched_barrier(0)
#define BAR do { SB0; __builtin_amdgcn_s_barrier(); SB0; } while (0)
#define WVM(N) do { asm volatile("s_waitcnt vmcnt(" #N ")" ::: "memory"); SB0; } while (0)
#define WLG0 do { asm volatile("s_waitcnt lgkmcnt(0)" ::: "memory"); SB0; } while (0)

#define LD_A1(KT)                                                          \
  do { SB0;                                                                \
    ar1[0][0] = *(const f32x4*)(sA0 + (KT));                               \
    ar1[0][1] = *(const f32x4*)(sA0 + (KT) + 4);                           \
    ar1[1][0] = *(const f32x4*)(sA1 + (KT));                               \
    ar1[1][1] = *(const f32x4*)(sA1 + (KT) + 4); SB0;                      \
  } while (0)
#define LD_A2(KT)                                                          \
  do { SB0;                                                                \
    ar2[0][0] = *(const f32x4*)(sA2 + (KT));                               \
    ar2[0][1] = *(const f32x4*)(sA2 + (KT) + 4);                           \
    ar2[1][0] = *(const f32x4*)(sA3 + (KT));                               \
    ar2[1][1] = *(const f32x4*)(sA3 + (KT) + 4); SB0;                      \
  } while (0)
#define WR_A(AR, BUF, OFS)                                                 \
  do {                                                                     \
    _Pragma("unroll") for (int j = 0; j < 2; ++j) {                        \
      u16x8 v;                                                             \
      _Pragma("unroll") for (int q = 0; q < 4; ++q) {                      \
        v[q]     = (unsigned short)f2bf(AR[j][0][q]);                      \
        v[4 + q] = (unsigned short)f2bf(AR[j][1][q]);                      \
      }                                                                    \
      *(u16x8*)(&As[BUF][adst + (OFS) + j * 4096]) = v;                    \
    }                                                                      \
  } while (0)
#define DMA_B2(KT, BUF, I0)                                                \
  do { SB0;                                                                \
    _Pragma("unroll") for (int i = (I0); i < (I0) + 2; ++i)                \
      load_lds16(b_src[i] + (KT), &Bs[BUF][b_dst[i]]);                     \
    SB0;                                                                   \
  } while (0)
#define RD_A(MH, AB)                                                       \
  do { SB0;                                                                \
    _Pragma("unroll") for (int mi = 0; mi < 4; ++mi) {                     \
      aF[0][mi] = *(const bf16x8*)((AB) + abase + ((MH)*4 + mi) * 1024 + axk0); \
      aF[1][mi] = *(const bf16x8*)((AB) + abase + ((MH)*4 + mi) * 1024 + axk1); \
    } SB0;                                                                 \
  } while (0)
#define RD_B(DST, NH, BB)                                                  \
  do { SB0;                                                                \
    _Pragma("unroll") for (int nj = 0; nj < 2; ++nj) {                     \
      DST[0][nj] = *(const bf16x8*)((BB) + bbase + ((NH)*2 + nj) * 1024 + axk0); \
      DST[1][nj] = *(const bf16x8*)((BB) + bbase + ((NH)*2 + nj) * 1024 + axk1); \
    } SB0;                                                                 \
  } while (0)
#define Q(MH, NH, BF)                                                      \
  do { __builtin_amdgcn_s_setprio(1);                                      \
    _Pragma("unroll") for (int kk = 0; kk < 2; ++kk)                       \
      _Pragma("unroll") for (int mi = 0; mi < 4; ++mi)                     \
        _Pragma("unroll") for (int nj = 0; nj < 2; ++nj)                   \
          acc[(MH)*4 + mi][(NH)*2 + nj] =                                  \
              __builtin_amdgcn_mfma_f32_16x16x32_bf16(                     \
                  aF[kk][mi], BF[kk][nj], acc[(MH)*4 + mi][(NH)*2 + nj],   \
                  0, 0, 0);                                                \
    __builtin_amdgcn_s_setprio(0);                                         \
  } while (0)

  // ---- prologue: A(0)->LDS(0), B(0) DMA in flight, A(1) regs in flight ----
  LD_A1(0); LD_A2(0);          // A(0) x8
  WVM(4); WR_A(ar1, 0, 0);     // h1 -> buf0
  WVM(0); WR_A(ar2, 0, 8192);  // h2 -> buf0
  DMA_B2(0, 0, 0); DMA_B2(0, 0, 2);   // B(0) x4
  LD_A1(BK); LD_A2(BK);               // A(1) x8
  WLG0;                        // drain A(0) ds_writes
  BAR;
  // queue now (old->new): [B(0):4, A(1)h1:4, A(1)h2:4]

  // ---- steady: tt = 0 .. NT-3 ----
  for (int tt = 0; tt < NT - 2; ++tt) {
    const int cur = tt & 1, nxt = cur ^ 1;
    const unsigned short* Ab = As[cur];
    const unsigned short* Bb = Bs[cur];
    const int kt1 = (tt + 1) * BK, kt2 = (tt + 2) * BK;
    // P1: [B(t):4, A(t+1):8] -> retire B(t)
    WVM(8);
    RD_A(0, Ab);
    RD_B(bF0, 0, Bb);
    BAR; WLG0;
    Q(0, 0, bF0);
    BAR;
    // P2: retire A(t+1)h1; cvt+write h1; read nh1; DMA B(t+1) h0
    WVM(4);
    WR_A(ar1, nxt, 0);
    RD_B(bF1, 1, Bb);
    DMA_B2(kt1, nxt, 0);
    BAR; WLG0;
    Q(0, 1, bF1);
    BAR;
    // P3: retire A(t+1)h2 (2 B-DMA stay); write h2; read mh1; DMA B h1; issue A(t+2)h1
    WVM(2);
    WR_A(ar2, nxt, 8192);
    RD_A(1, Ab);
    DMA_B2(kt1, nxt, 2);
    LD_A1(kt2);
    BAR; WLG0;
    Q(1, 1, bF1);
    BAR;
    // P4: issue A(t+2)h2; q10; publish (A writes drained by P3's WLG0)
    LD_A2(kt2);
    Q(1, 0, bF0);
    BAR;
  }

  // ---- tile NT-2: steady minus A(t+2) issues ----
  {
    const int cur = (NT - 2) & 1, nxt = cur ^ 1;
    const unsigned short* Ab = As[cur];
    const unsigned short* Bb = Bs[cur];
    const int kt1 = (NT - 1) * BK;
    WVM(8);
    RD_A(0, Ab);
    RD_B(bF0, 0, Bb);
    BAR; WLG0;
    Q(0, 0, bF0);
    BAR;
    WVM(4);
    WR_A(ar1, nxt, 0);
    RD_B(bF1, 1, Bb);
    DMA_B2(kt1, nxt, 0);
    BAR; WLG0;
    Q(0, 1, bF1);
    BAR;
    WVM(2);
    WR_A(ar2, nxt, 8192);
    RD_A(1, Ab);
    DMA_B2(kt1, nxt, 2);
    BAR; WLG0;
    Q(1, 1, bF1);
    BAR;
    Q(1, 0, bF0);
    BAR;
  }
  // ---- last tile NT-1: pure compute; only [B(NT-1):4] in flight ----
  {
    const unsigned short* Ab = As[(NT - 1) & 1];
    const unsigned short* Bb = Bs[(NT - 1) & 1];
    WVM(0);
    RD_A(0, Ab);
    RD_B(bF0, 0, Bb);
    WLG0;
    Q(0, 0, bF0);
    RD_B(bF1, 1, Bb);
    WLG0;
    Q(0, 1, bF1);
    RD_A(1, Ab);
    WLG0;
    Q(1, 1, bF1);
    Q(1, 0, bF0);
  }

  // ---- epilogue: + sign(bias); D frag: col = l&15, row = (l>>4)*4 + j ----
#pragma unroll
  for (int ni = 0; ni < 4; ++ni) {
    const int col = n0 + wn * 64 + ni * 16 + (l & 15);
    const float b  = bias[col];
    const float bs = (b > 0.f) ? 1.f : ((b < 0.f) ? -1.f : 0.f);
#pragma unroll
    for (int mi = 0; mi < 8; ++mi) {
      const int row = m0 + wm * 128 + mi * 16 + ((l >> 4) << 2);
#pragma unroll
      for (int j = 0; j < 4; ++j)
        Z[(size_t)(row + j) * N_DIM + col] = acc[mi][ni][j] + bs;
    }
  }
#undef SB0
#undef BAR
#undef WVM
#undef WLG0
#undef LD_A1
#undef LD_A2
#undef WR_A
#undef DMA_B2
#undef RD_A
#undef RD_B
#undef Q
}

// ---------- slow-but-correct fallback ----------
__global__ __launch_bounds__(256) void naive_fb(
    const float* __restrict__ X, const float* __restrict__ W,
    const float* __restrict__ bias, float* __restrict__ Z) {
  const size_t id = (size_t)blockIdx.x * 256 + threadIdx.x;
  const int m = (int)(id >> 10), n = (int)(id & 1023);
  float acc = 0.f;
  for (int k = 0; k < K_DIM; ++k) {
    const float w = W[(size_t)k * N_DIM + n];
    const float s = (w > 0.f) ? 1.f : ((w < 0.f) ? -1.f : 0.f);
    acc += X[(size_t)m * K_DIM + k] * s;
  }
  const float b = bias[n];
  Z[id] = acc + ((b > 0.f) ? 1.f : ((b < 0.f) ? -1.f : 0.f));
}

extern "C" void kernel_launch(void* const* d_in, const int* in_sizes, int n_in,
                              void* d_out, int out_size, void* d_ws, size_t ws_size,
                              hipStream_t stream) {
  const float* X    = (const float*)d_in[0];
  const float* W    = (const float*)d_in[1];
  const float* bias = (const float*)d_in[2];
  float* Z = (float*)d_out;

  const size_t needW = (size_t)N_DIM * K_DIM * sizeof(unsigned short);  // 8 MiB
  if (ws_size >= needW) {
    unsigned short* WbT = (unsigned short*)d_ws;
    wsign_transpose<<<dim3((K_DIM / 64) * (N_DIM / 64)), dim3(256), 0, stream>>>(W, WbT);
    gemm_p4<<<dim3((M_DIM / BM) * (N_DIM / BN)), dim3(512), 0, stream>>>(X, WbT, bias, Z);
  } else {
    naive_fb<<<dim3((size_t)M_DIM * N_DIM / 256), dim3(256), 0, stream>>>(X, W, bias, Z);
  }
}

// Round 8
// 177.641 us; speedup vs baseline: 3.2526x; 1.0530x over previous
//
#include <hip/hip_runtime.h>

#define M_DIM 16384
#define N_DIM 1024
#define K_DIM 4096

#define BM 256
#define BN 256
#define BK 64
#define NT (K_DIM / BK)

typedef __attribute__((ext_vector_type(4))) float f32x4;
typedef __attribute__((ext_vector_type(8))) short bf16x8;
typedef __attribute__((ext_vector_type(8))) unsigned short u16x8;

static __device__ __forceinline__ short f2bf(float f) {
  union { __bf16 h; short s; } u;
  u.h = (__bf16)f;   // RNE; pairs pack into v_cvt_pk_bf16_f32
  return u.s;
}

static __device__ __forceinline__ void load_lds16(const void* g, void* l) {
  __builtin_amdgcn_global_load_lds(
      (const __attribute__((address_space(1))) void*)g,
      (__attribute__((address_space(3))) void*)l, 16, 0, 0);
}

// ---------- prepass: WbT[n][k] = bf16(sign(W[k][n])) ----------
__global__ __launch_bounds__(256) void wsign_transpose(
    const float* __restrict__ W, unsigned short* __restrict__ WbT) {
  __shared__ unsigned short tile[64][72];
  const int t  = (int)threadIdx.x;
  const int k0 = (int)(blockIdx.x >> 4) * 64;
  const int n0 = (int)(blockIdx.x & 15) * 64;
#pragma unroll
  for (int p = 0; p < 4; ++p) {
    const int r = p * 16 + (t >> 4);
    const int c = (t & 15) * 4;
    const float* src = W + (size_t)(k0 + r) * N_DIM + n0 + c;
#pragma unroll
    for (int j = 0; j < 4; ++j) {
      const float w = src[j];
      tile[r][c + j] = (w > 0.f) ? (unsigned short)0x3F80u
                                 : ((w < 0.f) ? (unsigned short)0xBF80u
                                              : (unsigned short)0u);
    }
  }
  __syncthreads();
  const int n  = t >> 2;
  const int kg = (t & 3) * 16;
  u16x8 o0, o1;
#pragma unroll
  for (int j = 0; j < 8; ++j) o0[j] = tile[kg + j][n];
#pragma unroll
  for (int j = 0; j < 8; ++j) o1[j] = tile[kg + 8 + j][n];
  unsigned short* dst = WbT + (size_t)(n0 + n) * K_DIM + k0 + kg;
  *(u16x8*)dst       = o0;
  *(u16x8*)(dst + 8) = o1;
}

// ---------- main GEMM: 256x256, BK=64, 8 waves, kk-major 4-phase ----------
// ph1: kk0*mi0-3 (8r), ph2: kk0*mi4-7 (4r, A-h1 write), ph3: kk1*mi0-3
// (8r, A-h2 write, A(t+2) issue), ph4: kk1*mi4-7 (4r, WVM(8)).
// Uniform read mix per phase; all vm waits counted; arch-VGPR ~100.
__global__ __launch_bounds__(512, 2) void gemm_kk(
    const float* __restrict__ X, const unsigned short* __restrict__ WbT,
    const float* __restrict__ bias, float* __restrict__ Z) {
  __shared__ __align__(16) unsigned short As[2][BM * BK];  // 64 KiB
  __shared__ __align__(16) unsigned short Bs[2][BN * BK];  // 64 KiB

  const int t   = (int)threadIdx.x;
  const int l   = t & 63;
  const int wid = t >> 6;
  const int wm  = wid >> 2;  // 0..1
  const int wn  = wid & 3;   // 0..3

  const int bid = (int)blockIdx.x;
  const int swz = (bid & 7) * 32 + (bid >> 3);  // bijective: 256 = 8*32
  const int m0  = (swz >> 2) * BM;
  const int n0  = (swz & 3) * BN;

  // fragment read offsets (XOR-swizzled; verified R1..R7)
  const int abase = (wm * 128 + (l & 15)) * BK;
  const int bbase = (wn * 64 + (l & 15)) * BK;
  const int axk0  = (((l >> 4) + 0) ^ (l & 7)) << 3;
  const int axk1  = (((l >> 4) + 4) ^ (l & 7)) << 3;

  // A staging: thread owns rows {i*64 + t>>3}, k-granule t&7
  const float* sA0 = X + (size_t)(m0 +   0 + (t >> 3)) * K_DIM + (t & 7) * 8;
  const float* sA1 = X + (size_t)(m0 +  64 + (t >> 3)) * K_DIM + (t & 7) * 8;
  const float* sA2 = X + (size_t)(m0 + 128 + (t >> 3)) * K_DIM + (t & 7) * 8;
  const float* sA3 = X + (size_t)(m0 + 192 + (t >> 3)) * K_DIM + (t & 7) * 8;
  const int adst = (t >> 3) * BK + (((t & 7) ^ ((t >> 3) & 7)) << 3);

  // B staging: linear LDS dest, inverse-swizzled global source
  const unsigned short* b_src[4];
  int b_dst[4];
#pragma unroll
  for (int i = 0; i < 4; ++i) {
    const int c = i * 512 + t;
    const int n = c >> 3, gp = c & 7;
    b_src[i] = WbT + (size_t)(n0 + n) * K_DIM + (gp ^ (n & 7)) * 8;
    b_dst[i] = c * 8;
  }

  f32x4 acc[8][4] = {};      // 128 acc regs
  f32x4 ar[4][2];            // A(t+1) staging, rows {0,64,128,192}+t>>3 (32)
  bf16x8 aR[4];              // current (kk, mi-group) A frags (16)
  bf16x8 bR[4];              // current kk B frags nj0-3 (16)

#define SB0 __builtin_amdgcn_sched_barrier(0)
#define BAR do { SB0; __builtin_amdgcn_s_barrier(); SB0; } while (0)
#define WVM(N) do { asm volatile("s_waitcnt vmcnt(" #N ")" ::: "memory"); SB0; } while (0)
#define WLG0 do { asm volatile("s_waitcnt lgkmcnt(0)" ::: "memory"); SB0; } while (0)

#define LD_A8(KT)                                                          \
  do { SB0;                                                                \
    ar[0][0] = *(const f32x4*)(sA0 + (KT));                                \
    ar[0][1] = *(const f32x4*)(sA0 + (KT) + 4);                            \
    ar[1][0] = *(const f32x4*)(sA1 + (KT));                                \
    ar[1][1] = *(const f32x4*)(sA1 + (KT) + 4);                            \
    ar[2][0] = *(const f32x4*)(sA2 + (KT));                                \
    ar[2][1] = *(const f32x4*)(sA2 + (KT) + 4);                            \
    ar[3][0] = *(const f32x4*)(sA3 + (KT));                                \
    ar[3][1] = *(const f32x4*)(sA3 + (KT) + 4); SB0;                       \
  } while (0)
#define WR_AH(BUF, H)                                                      \
  do {                                                                     \
    _Pragma("unroll") for (int j = 2 * (H); j < 2 * (H) + 2; ++j) {        \
      u16x8 v;                                                             \
      _Pragma("unroll") for (int q = 0; q < 4; ++q) {                      \
        v[q]     = (unsigned short)f2bf(ar[j][0][q]);                      \
        v[4 + q] = (unsigned short)f2bf(ar[j][1][q]);                      \
      }                                                                    \
      *(u16x8*)(&As[BUF][adst + j * 4096]) = v;                            \
    }                                                                      \
  } while (0)
#define DMA_B2(KT, BUF, I0)                                                \
  do { SB0;                                                                \
    _Pragma("unroll") for (int i = (I0); i < (I0) + 2; ++i)                \
      load_lds16(b_src[i] + (KT), &Bs[BUF][b_dst[i]]);                     \
    SB0;                                                                   \
  } while (0)
#define RD_A4(KK, MIG, AB)                                                 \
  do { SB0;                                                                \
    _Pragma("unroll") for (int mi = 0; mi < 4; ++mi)                       \
      aR[mi] = *(const bf16x8*)((AB) + abase + ((MIG)*4 + mi) * 1024 +     \
                                ((KK) ? axk1 : axk0));                     \
    SB0;                                                                   \
  } while (0)
#define RD_B4(KK, BB)                                                      \
  do { SB0;                                                                \
    _Pragma("unroll") for (int nj = 0; nj < 4; ++nj)                       \
      bR[nj] = *(const bf16x8*)((BB) + bbase + nj * 1024 +                 \
                                ((KK) ? axk1 : axk0));                     \
    SB0;                                                                   \
  } while (0)
#define MFMA16(MIG)                                                        \
  do { __builtin_amdgcn_s_setprio(1);                                      \
    _Pragma("unroll") for (int mi = 0; mi < 4; ++mi)                       \
      _Pragma("unroll") for (int nj = 0; nj < 4; ++nj)                     \
        acc[(MIG)*4 + mi][nj] = __builtin_amdgcn_mfma_f32_16x16x32_bf16(   \
            aR[mi], bR[nj], acc[(MIG)*4 + mi][nj], 0, 0, 0);               \
    __builtin_amdgcn_s_setprio(0);                                         \
  } while (0)

  // ---- prologue: A(0)+B(0) -> buf0; A(1) regs in flight ----
  LD_A8(0);
  WVM(0);
  WR_AH(0, 0); WR_AH(0, 1);
  DMA_B2(0, 0, 0); DMA_B2(0, 0, 2);   // B(0) x4
  LD_A8(BK);                          // A(1) x8 in flight
  WVM(8);                             // retire B(0); leave A(1) x8
  WLG0;                               // drain A(0) ds_writes
  BAR;
  // steady entry state: vmem [A(t+1) x8]; lgkm empty

  // ---- steady: tt = 0 .. NT-3 ----
  for (int tt = 0; tt <= NT - 3; ++tt) {
    const int cur = tt & 1, nxt = cur ^ 1;
    const unsigned short* Ab = As[cur];
    const unsigned short* Bb = Bs[cur];
    const int kt1 = (tt + 1) * BK, kt2 = (tt + 2) * BK;
    // PH1: kk0, mi0-3  (8 reads; issue B(t+1) h0)
    RD_B4(0, Bb);
    RD_A4(0, 0, Ab);
    DMA_B2(kt1, nxt, 0);
    BAR; WLG0;
    MFMA16(0);
    BAR;
    // PH2: kk0, mi4-7  (4 reads; retire A(t+1) regs; write h1; issue B h1)
    RD_A4(0, 1, Ab);
    DMA_B2(kt1, nxt, 2);
    WVM(4);                  // retire A(t+1) x8; leave B(t+1) x4
    WR_AH(nxt, 0);
    BAR; WLG0;
    MFMA16(1);
    BAR;
    // PH3: kk1, mi0-3  (8 reads; write h2; issue A(t+2))
    RD_B4(1, Bb);
    RD_A4(1, 0, Ab);
    WR_AH(nxt, 1);           // uses old ar (reads at issue), then reload
    LD_A8(kt2);
    BAR; WLG0;
    MFMA16(0);
    BAR;
    // PH4: kk1, mi4-7  (4 reads; retire B(t+1) before publish)
    RD_A4(1, 1, Ab);
    WVM(8);                  // retire B(t+1) x4; leave A(t+2) x8
    BAR; WLG0;
    MFMA16(1);
    BAR;                     // publish tile t+1
  }

  // ---- tile NT-2: steady minus A(t+2) issue ----
  {
    const int cur = (NT - 2) & 1, nxt = cur ^ 1;
    const unsigned short* Ab = As[cur];
    const unsigned short* Bb = Bs[cur];
    const int kt1 = (NT - 1) * BK;
    RD_B4(0, Bb);
    RD_A4(0, 0, Ab);
    DMA_B2(kt1, nxt, 0);
    BAR; WLG0;
    MFMA16(0);
    BAR;
    RD_A4(0, 1, Ab);
    DMA_B2(kt1, nxt, 2);
    WVM(4);
    WR_AH(nxt, 0);
    BAR; WLG0;
    MFMA16(1);
    BAR;
    RD_B4(1, Bb);
    RD_A4(1, 0, Ab);
    WR_AH(nxt, 1);
    BAR; WLG0;
    MFMA16(0);
    BAR;
    RD_A4(1, 1, Ab);
    WVM(0);                  // only stale B(NT-1) x4 pending
    BAR; WLG0;
    MFMA16(1);
    BAR;
  }
  // ---- tile NT-1: pure compute (no barriers needed) ----
  {
    const unsigned short* Ab = As[(NT - 1) & 1];
    const unsigned short* Bb = Bs[(NT - 1) & 1];
    RD_B4(0, Bb);
    RD_A4(0, 0, Ab);
    WLG0;
    MFMA16(0);
    RD_A4(0, 1, Ab);
    WLG0;
    MFMA16(1);
    RD_B4(1, Bb);
    RD_A4(1, 0, Ab);
    WLG0;
    MFMA16(0);
    RD_A4(1, 1, Ab);
    WLG0;
    MFMA16(1);
  }

  // ---- epilogue: + sign(bias); D frag: col = l&15, row = (l>>4)*4 + j ----
#pragma unroll
  for (int ni = 0; ni < 4; ++ni) {
    const int col = n0 + wn * 64 + ni * 16 + (l & 15);
    const float b  = bias[col];
    const float bs = (b > 0.f) ? 1.f : ((b < 0.f) ? -1.f : 0.f);
#pragma unroll
    for (int mi = 0; mi < 8; ++mi) {
      const int row = m0 + wm * 128 + mi * 16 + ((l >> 4) << 2);
#pragma unroll
      for (int j = 0; j < 4; ++j)
        Z[(size_t)(row + j) * N_DIM + col] = acc[mi][ni][j] + bs;
    }
  }
#undef SB0
#undef BAR
#undef WVM
#undef WLG0
#undef LD_A8
#undef WR_AH
#undef DMA_B2
#undef RD_A4
#undef RD_B4
#undef MFMA16
}

// ---------- slow-but-correct fallback ----------
__global__ __launch_bounds__(256) void naive_fb(
    const float* __restrict__ X, const float* __restrict__ W,
    const float* __restrict__ bias, float* __restrict__ Z) {
  const size_t id = (size_t)blockIdx.x * 256 + threadIdx.x;
  const int m = (int)(id >> 10), n = (int)(id & 1023);
  float acc = 0.f;
  for (int k = 0; k < K_DIM; ++k) {
    const float w = W[(size_t)k * N_DIM + n];
    const float s = (w > 0.f) ? 1.f : ((w < 0.f) ? -1.f : 0.f);
    acc += X[(size_t)m * K_DIM + k] * s;
  }
  const float b = bias[n];
  Z[id] = acc + ((b > 0.f) ? 1.f : ((b < 0.f) ? -1.f : 0.f));
}

extern "C" void kernel_launch(void* const* d_in, const int* in_sizes, int n_in,
                              void* d_out, int out_size, void* d_ws, size_t ws_size,
                              hipStream_t stream) {
  const float* X    = (const float*)d_in[0];
  const float* W    = (const float*)d_in[1];
  const float* bias = (const float*)d_in[2];
  float* Z = (float*)d_out;

  const size_t needW = (size_t)N_DIM * K_DIM * sizeof(unsigned short);  // 8 MiB
  if (ws_size >= needW) {
    unsigned short* WbT = (unsigned short*)d_ws;
    wsign_transpose<<<dim3((K_DIM / 64) * (N_DIM / 64)), dim3(256), 0, stream>>>(W, WbT);
    gemm_kk<<<dim3((M_DIM / BM) * (N_DIM / BN)), dim3(512), 0, stream>>>(X, WbT, bias, Z);
  } else {
    naive_fb<<<dim3((size_t)M_DIM * N_DIM / 256), dim3(256), 0, stream>>>(X, W, bias, Z);
  }
}

// Round 9
// 172.171 us; speedup vs baseline: 3.3559x; 1.0318x over previous
//
#include <hip/hip_runtime.h>

#define M_DIM 16384
#define N_DIM 1024
#define K_DIM 4096

#define BM 256
#define BN 256
#define BK 64
#define NT (K_DIM / BK)

typedef __attribute__((ext_vector_type(4))) float f32x4;
typedef __attribute__((ext_vector_type(8))) short bf16x8;
typedef __attribute__((ext_vector_type(8))) unsigned short u16x8;

static __device__ __forceinline__ short f2bf(float f) {
  union { __bf16 h; short s; } u;
  u.h = (__bf16)f;   // RNE; pairs pack into v_cvt_pk_bf16_f32
  return u.s;
}

static __device__ __forceinline__ void load_lds16(const void* g, void* l) {
  __builtin_amdgcn_global_load_lds(
      (const __attribute__((address_space(1))) void*)g,
      (__attribute__((address_space(3))) void*)l, 16, 0, 0);
}

// ---------- prepass: WbT[n][k] = bf16(sign(W[k][n])) ----------
__global__ __launch_bounds__(256) void wsign_transpose(
    const float* __restrict__ W, unsigned short* __restrict__ WbT) {
  __shared__ unsigned short tile[64][67];  // 67: break bank alignment on col reads
  const int t  = (int)threadIdx.x;
  const int k0 = (int)(blockIdx.x >> 4) * 64;
  const int n0 = (int)(blockIdx.x & 15) * 64;
#pragma unroll
  for (int p = 0; p < 4; ++p) {
    const int r = p * 16 + (t >> 4);
    const int c = (t & 15) * 4;
    const float* src = W + (size_t)(k0 + r) * N_DIM + n0 + c;
#pragma unroll
    for (int j = 0; j < 4; ++j) {
      const float w = src[j];
      tile[r][c + j] = (w > 0.f) ? (unsigned short)0x3F80u
                                 : ((w < 0.f) ? (unsigned short)0xBF80u
                                              : (unsigned short)0u);
    }
  }
  __syncthreads();
  const int n  = t >> 2;
  const int kg = (t & 3) * 16;
  u16x8 o0, o1;
#pragma unroll
  for (int j = 0; j < 8; ++j) o0[j] = tile[kg + j][n];
#pragma unroll
  for (int j = 0; j < 8; ++j) o1[j] = tile[kg + 8 + j][n];
  unsigned short* dst = WbT + (size_t)(n0 + n) * K_DIM + k0 + kg;
  *(u16x8*)dst       = o0;
  *(u16x8*)(dst + 8) = o1;
}

// ---------- main GEMM: 256x256, BK=64, 8 waves, counted-lgkm pipeline ----------
// Each phase issues NEXT quadrant's ds_reads; MFMA waits on a COUNTED lgkm
// that retires only the prior batch. 2 barriers/K-tile (publish, overwrite).
// Quadrants: ph1=(kk0,m0) ph2=(kk0,m1) ph3=(kk1,m0) ph4=(kk1,m1).
__global__ __launch_bounds__(512, 2) void gemm_pipe(
    const float* __restrict__ X, const unsigned short* __restrict__ WbT,
    const float* __restrict__ bias, float* __restrict__ Z) {
  __shared__ __align__(16) unsigned short As[2][BM * BK];  // 64 KiB
  __shared__ __align__(16) unsigned short Bs[2][BN * BK];  // 64 KiB

  const int t   = (int)threadIdx.x;
  const int l   = t & 63;
  const int wid = t >> 6;
  const int wm  = wid >> 2;  // 0..1
  const int wn  = wid & 3;   // 0..3

  const int bid = (int)blockIdx.x;
  const int swz = (bid & 7) * 32 + (bid >> 3);  // bijective: 256 = 8*32
  const int m0  = (swz >> 2) * BM;
  const int n0  = (swz & 3) * BN;

  const int abase = (wm * 128 + (l & 15)) * BK;
  const int bbase = (wn * 64 + (l & 15)) * BK;
  const int axk0  = (((l >> 4) + 0) ^ (l & 7)) << 3;
  const int axk1  = (((l >> 4) + 4) ^ (l & 7)) << 3;

  // A staging: thread owns rows {i*64 + t>>3}, k-granule t&7
  const float* sA0 = X + (size_t)(m0 +   0 + (t >> 3)) * K_DIM + (t & 7) * 8;
  const float* sA1 = X + (size_t)(m0 +  64 + (t >> 3)) * K_DIM + (t & 7) * 8;
  const float* sA2 = X + (size_t)(m0 + 128 + (t >> 3)) * K_DIM + (t & 7) * 8;
  const float* sA3 = X + (size_t)(m0 + 192 + (t >> 3)) * K_DIM + (t & 7) * 8;
  const int adst = (t >> 3) * BK + (((t & 7) ^ ((t >> 3) & 7)) << 3);

  // B staging: linear LDS dest, inverse-swizzled global source
  const unsigned short* b_src[4];
  int b_dst[4];
#pragma unroll
  for (int i = 0; i < 4; ++i) {
    const int c = i * 512 + t;
    const int n = c >> 3, gp = c & 7;
    b_src[i] = WbT + (size_t)(n0 + n) * K_DIM + (gp ^ (n & 7)) * 8;
    b_dst[i] = c * 8;
  }

  f32x4 acc[8][4] = {};      // 128 acc regs
  f32x4 ar[4][2];            // A(t+1) staging (32)
  bf16x8 a0F[4], a1F[4];     // ping/pong A frags (16+16)
  bf16x8 b0F[4], b1F[4];     // kk0 / kk1 B frags (16+16)

#define SB0 __builtin_amdgcn_sched_barrier(0)
#define BAR do { SB0; __builtin_amdgcn_s_barrier(); SB0; } while (0)
#define WVM(N) do { asm volatile("s_waitcnt vmcnt(" #N ")" ::: "memory"); SB0; } while (0)
#define WLG(N) do { asm volatile("s_waitcnt lgkmcnt(" #N ")" ::: "memory"); SB0; } while (0)

#define LD_A8(KT)                                                          \
  do { SB0;                                                                \
    ar[0][0] = *(const f32x4*)(sA0 + (KT));                                \
    ar[0][1] = *(const f32x4*)(sA0 + (KT) + 4);                            \
    ar[1][0] = *(const f32x4*)(sA1 + (KT));                                \
    ar[1][1] = *(const f32x4*)(sA1 + (KT) + 4);                            \
    ar[2][0] = *(const f32x4*)(sA2 + (KT));                                \
    ar[2][1] = *(const f32x4*)(sA2 + (KT) + 4);                            \
    ar[3][0] = *(const f32x4*)(sA3 + (KT));                                \
    ar[3][1] = *(const f32x4*)(sA3 + (KT) + 4); SB0;                       \
  } while (0)
#define WR_AH(BUF, H)                                                      \
  do { SB0;                                                                \
    _Pragma("unroll") for (int j = 2 * (H); j < 2 * (H) + 2; ++j) {        \
      u16x8 v;                                                             \
      _Pragma("unroll") for (int q = 0; q < 4; ++q) {                      \
        v[q]     = (unsigned short)f2bf(ar[j][0][q]);                      \
        v[4 + q] = (unsigned short)f2bf(ar[j][1][q]);                      \
      }                                                                    \
      *(u16x8*)(&As[BUF][adst + j * 4096]) = v;                            \
    } SB0;                                                                 \
  } while (0)
#define DMA_B4(KT, BUF)                                                    \
  do { SB0;                                                                \
    _Pragma("unroll") for (int i = 0; i < 4; ++i)                          \
      load_lds16(b_src[i] + (KT), &Bs[BUF][b_dst[i]]);                     \
    SB0;                                                                   \
  } while (0)
#define RD_A(DST, KK, MIG, AB)                                             \
  do { SB0;                                                                \
    _Pragma("unroll") for (int mi = 0; mi < 4; ++mi)                       \
      DST[mi] = *(const bf16x8*)((AB) + abase + ((MIG)*4 + mi) * 1024 +    \
                                 ((KK) ? axk1 : axk0));                    \
    SB0;                                                                   \
  } while (0)
#define RD_B(DST, KK, BB)                                                  \
  do { SB0;                                                                \
    _Pragma("unroll") for (int nj = 0; nj < 4; ++nj)                       \
      DST[nj] = *(const bf16x8*)((BB) + bbase + nj * 1024 +                \
                                 ((KK) ? axk1 : axk0));                    \
    SB0;                                                                   \
  } while (0)
#define MFMA16(MIG, AF, BF)                                                \
  do { __builtin_amdgcn_s_setprio(1);                                      \
    _Pragma("unroll") for (int mi = 0; mi < 4; ++mi)                       \
      _Pragma("unroll") for (int nj = 0; nj < 4; ++nj)                     \
        acc[(MIG)*4 + mi][nj] = __builtin_amdgcn_mfma_f32_16x16x32_bf16(   \
            AF[mi], BF[nj], acc[(MIG)*4 + mi][nj], 0, 0, 0);               \
    __builtin_amdgcn_s_setprio(0);                                         \
  } while (0)

  // ---- prologue ----
  LD_A8(0);                      // A(0) x8 vm
  WVM(0);
  WR_AH(0, 0); WR_AH(0, 1);      // A(0) -> buf0 (4w)
  DMA_B4(0, 0);                  // B(0) x4 vm
  LD_A8(BK);                     // A(1) x8 vm -> [B(0):4, A(1):8]
  WVM(8);                        // retire B(0)
  WLG(0);                        // drain A(0) writes
  BAR;                           // publish buf0
  RD_A(a0F, 0, 0, As[0]);        // lgkm [a0:4]
  RD_B(b0F, 0, Bs[0]);           // lgkm [a0:4, b0:4]
  // invariant: lgkm [a0:4, b0:4]; vm [A(t+1):8]

  // ---- steady: tt = 0 .. NT-3 ----
  for (int tt = 0; tt <= NT - 3; ++tt) {
    const int cur = tt & 1, nxt = cur ^ 1;
    const unsigned short* Ab = As[cur];
    const unsigned short* Bb = Bs[cur];
    // PH1 (kk0,m0): issue a1 <- (kk0,m1); B(t+1) DMA
    RD_A(a1F, 0, 1, Ab);         // lgkm [a0:4, b0:4, a1:4]
    DMA_B4((tt + 1) * BK, nxt);  // vm [A(t+1):8, B(t+1):4]
    WLG(4);                      // retire a0,b0
    MFMA16(0, a0F, b0F);
    // PH2 (kk0,m1): issue a0 <- (kk1,m0), b1 <- kk1; A(t+1) regs -> h1
    RD_A(a0F, 1, 0, Ab);
    RD_B(b1F, 1, Bb);            // lgkm [a1:4, a0:4, b1:4]
    WVM(4);                      // retire A(t+1) x8
    WR_AH(nxt, 0);               // lgkm [a1, a0, b1, w2]
    WLG(10);                     // retire a1
    MFMA16(1, a1F, b0F);
    // PH3 (kk1,m0): write h2; issue a1 <- (kk1,m1); issue A(t+2); publish
    WR_AH(nxt, 1);               // lgkm [a0, b1, w2, w2]
    RD_A(a1F, 1, 1, Ab);         // lgkm [a0, b1, w2, w2, a1]
    LD_A8((tt + 2) * BK);        // vm [B(t+1):4, A(t+2):8]
    WVM(8);                      // retire B(t+1) (publish requirement)
    WLG(4);                      // retire a0,b1,all writes; a1 stays
    MFMA16(0, a0F, b1F);
    BAR;                         // publish nxt
    // PH4 (kk1,m1): issue next tile's a0,b0 from nxt
    RD_A(a0F, 0, 0, As[nxt]);
    RD_B(b0F, 0, Bs[nxt]);       // lgkm [a1:4, a0:4, b0:4]
    WLG(8);                      // retire a1
    MFMA16(1, a1F, b1F);
    BAR;                         // anti-overwrite for cur
  }

  // ---- tile NT-2: steady minus LD_A8 ----
  {
    const int cur = (NT - 2) & 1, nxt = cur ^ 1;
    const unsigned short* Ab = As[cur];
    const unsigned short* Bb = Bs[cur];
    RD_A(a1F, 0, 1, Ab);
    DMA_B4((NT - 1) * BK, nxt);
    WLG(4);
    MFMA16(0, a0F, b0F);
    RD_A(a0F, 1, 0, Ab);
    RD_B(b1F, 1, Bb);
    WVM(4);                      // retire A(NT-1) x8
    WR_AH(nxt, 0);
    WLG(10);
    MFMA16(1, a1F, b0F);
    WR_AH(nxt, 1);
    RD_A(a1F, 1, 1, Ab);
    WVM(0);                      // retire B(NT-1) (nothing else in flight)
    WLG(4);
    MFMA16(0, a0F, b1F);
    BAR;                         // publish
    RD_A(a0F, 0, 0, As[nxt]);
    RD_B(b0F, 0, Bs[nxt]);
    WLG(8);
    MFMA16(1, a1F, b1F);
    BAR;
  }
  // ---- tile NT-1: pure compute ----
  {
    const unsigned short* Ab = As[(NT - 1) & 1];
    const unsigned short* Bb = Bs[(NT - 1) & 1];
    RD_A(a1F, 0, 1, Ab);
    WLG(4);
    MFMA16(0, a0F, b0F);
    RD_A(a0F, 1, 0, Ab);
    RD_B(b1F, 1, Bb);
    WLG(8);
    MFMA16(1, a1F, b0F);
    RD_A(a1F, 1, 1, Ab);
    WLG(4);
    MFMA16(0, a0F, b1F);
    WLG(0);
    MFMA16(1, a1F, b1F);
  }

  // ---- epilogue: + sign(bias); D frag: col = l&15, row = (l>>4)*4 + j ----
#pragma unroll
  for (int ni = 0; ni < 4; ++ni) {
    const int col = n0 + wn * 64 + ni * 16 + (l & 15);
    const float b  = bias[col];
    const float bs = (b > 0.f) ? 1.f : ((b < 0.f) ? -1.f : 0.f);
#pragma unroll
    for (int mi = 0; mi < 8; ++mi) {
      const int row = m0 + wm * 128 + mi * 16 + ((l >> 4) << 2);
#pragma unroll
      for (int j = 0; j < 4; ++j)
        Z[(size_t)(row + j) * N_DIM + col] = acc[mi][ni][j] + bs;
    }
  }
#undef SB0
#undef BAR
#undef WVM
#undef WLG
#undef LD_A8
#undef WR_AH
#undef DMA_B4
#undef RD_A
#undef RD_B
#undef MFMA16
}

// ---------- slow-but-correct fallback ----------
__global__ __launch_bounds__(256) void naive_fb(
    const float* __restrict__ X, const float* __restrict__ W,
    const float* __restrict__ bias, float* __restrict__ Z) {
  const size_t id = (size_t)blockIdx.x * 256 + threadIdx.x;
  const int m = (int)(id >> 10), n = (int)(id & 1023);
  float acc = 0.f;
  for (int k = 0; k < K_DIM; ++k) {
    const float w = W[(size_t)k * N_DIM + n];
    const float s = (w > 0.f) ? 1.f : ((w < 0.f) ? -1.f : 0.f);
    acc += X[(size_t)m * K_DIM + k] * s;
  }
  const float b = bias[n];
  Z[id] = acc + ((b > 0.f) ? 1.f : ((b < 0.f) ? -1.f : 0.f));
}

extern "C" void kernel_launch(void* const* d_in, const int* in_sizes, int n_in,
                              void* d_out, int out_size, void* d_ws, size_t ws_size,
                              hipStream_t stream) {
  const float* X    = (const float*)d_in[0];
  const float* W    = (const float*)d_in[1];
  const float* bias = (const float*)d_in[2];
  float* Z = (float*)d_out;

  const size_t needW = (size_t)N_DIM * K_DIM * sizeof(unsigned short);  // 8 MiB
  if (ws_size >= needW) {
    unsigned short* WbT = (unsigned short*)d_ws;
    wsign_transpose<<<dim3((K_DIM / 64) * (N_DIM / 64)), dim3(256), 0, stream>>>(W, WbT);
    gemm_pipe<<<dim3((M_DIM / BM) * (N_DIM / BN)), dim3(512), 0, stream>>>(X, WbT, bias, Z);
  } else {
    naive_fb<<<dim3((size_t)M_DIM * N_DIM / 256), dim3(256), 0, stream>>>(X, W, bias, Z);
  }
}